// Round 5
// baseline (831.961 us; speedup 1.0000x reference)
//
#include <hip/hip_runtime.h>
#include <hip/hip_fp16.h>

#define BSZ 256
#define CCH 512
#define HW_ 81
#define DD 9
#define CH 41472   /* CCH*HW_ */

/* ws layout (floats) */
#define WS_W1T   0        /* [162][81] folded+transposed se_att_w1 (legacy, unused) */
#define WS_TSE   13122    /* [81]  folded se_att bias */
#define WS_S2    13203    /* [512] sa_key bn scale */
#define WS_T2    13715    /* [512] sa_key bn bias */
#define WS_W1S   14227    /* [512][16] folded sa_att_w1 */
#define WS_T1    22419    /* [512] folded sa_att bias */
#define WS_A2    22932    /* [256][64][81] SaMCA attention */
#define WS_ATT   1350036  /* [256][9][512] SeMCA attention */
#define WS_W1F   2529684  /* [96][192] fp16 folded se_att_w1, zero-padded (ushorts) */
#define WS_TOTALP 22931   /* params region end */
#define PREP_N   41363    /* 22931 + 96*192 */

#define KST 40            /* kqT row stride in elements (80 B, 16B-aligned) */

typedef _Float16 half8 __attribute__((ext_vector_type(8)));
typedef float f32x4 __attribute__((ext_vector_type(4)));

__device__ __forceinline__ float h2f(unsigned short u) {
    return __half2float(__ushort_as_half(u));
}
__device__ __forceinline__ unsigned short f2h(float f) {
    return __half_as_ushort(__float2half(f));
}

__global__ void prep_kernel(const float* __restrict__ se_att_w1,  // 81*162
                            const float* __restrict__ se_att_bn,  // 4*81
                            const float* __restrict__ sa_key_bn,  // 4*512
                            const float* __restrict__ sa_att_w1,  // 512*16
                            const float* __restrict__ sa_att_bn,  // 4*512
                            float* __restrict__ ws) {
    int idx = blockIdx.x * blockDim.x + threadIdx.x;
    if (idx < 13122) {
        int r = idx / 81, o = idx % 81;
        float g = se_att_bn[o], v = se_att_bn[243 + o];
        float s = g * rsqrtf(v + 1e-5f);
        ws[WS_W1T + idx] = se_att_w1[o * 162 + r] * s;
    } else if (idx < 13203) {
        int o = idx - 13122;
        float g = se_att_bn[o], b = se_att_bn[81 + o], m = se_att_bn[162 + o], v = se_att_bn[243 + o];
        float s = g * rsqrtf(v + 1e-5f);
        ws[WS_TSE + o] = b - m * s;
    } else if (idx < 13715) {
        int c = idx - 13203;
        float g = sa_key_bn[c], v = sa_key_bn[1536 + c];
        ws[WS_S2 + c] = g * rsqrtf(v + 1e-5f);
    } else if (idx < 14227) {
        int c = idx - 13715;
        float g = sa_key_bn[c], b = sa_key_bn[512 + c], m = sa_key_bn[1024 + c], v = sa_key_bn[1536 + c];
        float s = g * rsqrtf(v + 1e-5f);
        ws[WS_T2 + c] = b - m * s;
    } else if (idx < 22419) {
        int e = idx - 14227;
        int o = e >> 4;
        float g = sa_att_bn[o], v = sa_att_bn[1536 + o];
        float s = g * rsqrtf(v + 1e-5f);
        ws[WS_W1S + e] = sa_att_w1[e] * s;
    } else if (idx < WS_TOTALP) {
        int o = idx - 22419;
        float g = sa_att_bn[o], b = sa_att_bn[512 + o], m = sa_att_bn[1024 + o], v = sa_att_bn[1536 + o];
        float s = g * rsqrtf(v + 1e-5f);
        ws[WS_T1 + o] = b - m * s;
    } else if (idx < PREP_N) {
        // fp16 folded W1, padded [96][192]: w1f[row][k] = se_att_w1[row*162+k]*scale(row)
        int e = idx - WS_TOTALP;
        int row = e / 192, k = e - row * 192;
        unsigned short val = 0;
        if (row < 81 && k < 162) {
            float g = se_att_bn[row], v = se_att_bn[243 + row];
            float s = g * rsqrtf(v + 1e-5f);
            val = f2h(se_att_w1[row * 162 + k] * s);
        }
        ((unsigned short*)(ws + WS_W1F))[e] = val;
    }
}

// ============== Kernel A: attention (P1 VALU + P2 MFMA), 1 block/batch ======
__global__ __launch_bounds__(1024) void attn_kernel(
    const float* __restrict__ x,
    const float* __restrict__ sa_key_w,   // 512*9
    const float* __restrict__ sa_att_w2,  // 64*8
    const float* __restrict__ sa_att_b2,  // 64
    const float* __restrict__ se_key_w,   // 81*9
    const float* __restrict__ se_key_b,   // 81
    const float* __restrict__ se_att_w2,  // 9*81
    const float* __restrict__ se_att_b2,  // 9
    float* __restrict__ ws)
{
    __shared__ __align__(16) unsigned short xb[CH];        // 82944 B, x fp16
    __shared__ __align__(16) unsigned short kqT[512 * KST];// 40960 B, KQ^T tile fp16
    __shared__ unsigned short wkb[CCH * DD];               //  9216 B
    __shared__ float wseT[DD * HW_];                       //  2916 B  (wseT[tau][p])
    __shared__ float bseb[HW_];                            //   324 B
    __shared__ float s2b[CCH];                             //  2048 B
    __shared__ float t2b[CCH];                             //  2048 B
    __shared__ float w2L[DD * 96];                         //  3456 B
    __shared__ float tseL[96];                             //   384 B
    /* total 144,296 B */

    const int b = blockIdx.x;
    const int t = threadIdx.x;

    // ---- P0: stage ----
    {
        const float4* x4 = (const float4*)(x + (size_t)b * CH);
        for (int v = t; v < CH / 4; v += 1024) {
            float4 q = x4[v];
            ushort4 s4;
            s4.x = f2h(q.x); s4.y = f2h(q.y); s4.z = f2h(q.z); s4.w = f2h(q.w);
            *(ushort4*)(&xb[4 * v]) = s4;
        }
        for (int v = t; v < CCH * DD; v += 1024) wkb[v] = f2h(sa_key_w[v]);
        if (t < DD * HW_) { int tau = t / 81, p = t - 81 * tau; wseT[tau * 81 + p] = se_key_w[p * 9 + tau]; }
        if (t < HW_) bseb[t] = se_key_b[t];
        if (t < CCH) { s2b[t] = ws[WS_S2 + t]; t2b[t] = ws[WS_T2 + t]; }
        if (t < DD * 96) { int d = t / 96, row = t - 96 * d; w2L[t] = (row < 81) ? se_att_w2[d * 81 + row] : 0.f; }
        if (t >= 1024 - 96) { int row = t - (1024 - 96); tseL[row] = (row < 81) ? ws[WS_TSE + row] : 0.f; }
    }
    __syncthreads();

    // ---- P1: SaMCA attention -> ws A2 (VALU; 64 groups x 16 lanes) ----
    {
        const int g = t >> 4, sub = t & 15;
        const float* w1sg = ws + WS_W1S;
        const float* t1g = ws + WS_T1;
        const float b2g = sa_att_b2[g];
        float a2v[6];
        #pragma unroll
        for (int k = 0; k < 6; ++k) {
            int p = sub + 16 * k;
            float res = -1e30f;
            if (p < 81) {
                int y = p / 9, xx = p - (p / 9) * 9;
                float z[8];
                #pragma unroll
                for (int o = 0; o < 8; ++o) z[o] = t1g[8 * g + o];
                #pragma unroll
                for (int j = 0; j < 8; ++j) {
                    int c = 8 * g + j;
                    float conv = 0.f;
                    #pragma unroll
                    for (int ky = 0; ky < 3; ++ky) {
                        int yy = y + ky - 1;
                        if (yy < 0 || yy > 8) continue;
                        #pragma unroll
                        for (int kx = 0; kx < 3; ++kx) {
                            int xc = xx + kx - 1;
                            if (xc < 0 || xc > 8) continue;
                            conv = fmaf(h2f(xb[c * 81 + yy * 9 + xc]),
                                        h2f(wkb[c * 9 + ky * 3 + kx]), conv);
                        }
                    }
                    float kv = fmaxf(conv * s2b[c] + t2b[c], 0.f);
                    float xv = h2f(xb[c * 81 + p]);
                    #pragma unroll
                    for (int o = 0; o < 8; ++o) {
                        const float* w1o = w1sg + (8 * g + o) * 16;
                        z[o] = fmaf(w1o[2 * j], kv, z[o]);
                        z[o] = fmaf(w1o[2 * j + 1], xv, z[o]);
                    }
                }
                float s = b2g;
                #pragma unroll
                for (int o = 0; o < 8; ++o)
                    s = fmaf(sa_att_w2[g * 8 + o], fmaxf(z[o], 0.f), s);
                res = s;
            }
            a2v[k] = res;
        }
        float m = a2v[0];
        #pragma unroll
        for (int k = 1; k < 6; ++k) m = fmaxf(m, a2v[k]);
        #pragma unroll
        for (int off = 1; off < 16; off <<= 1) m = fmaxf(m, __shfl_xor(m, off, 64));
        float ls = 0.f;
        float ev[6];
        #pragma unroll
        for (int k = 0; k < 6; ++k) { ev[k] = __expf(a2v[k] - m); ls += ev[k]; }
        #pragma unroll
        for (int off = 1; off < 16; off <<= 1) ls += __shfl_xor(ls, off, 64);
        float inv = 1.f / ls;
        float* a2out = ws + WS_A2 + (size_t)b * 5184;
        #pragma unroll
        for (int k = 0; k < 6; ++k) {
            int p = sub + 16 * k;
            if (p < 81) a2out[g * 81 + p] = ev[k] * inv;
        }
    }

    // ---- P2: SeMCA attention via MFMA ----
    // C[96 x 512] = W1f[96 x 192] * KQ[192 x 512]; KQ row r<81 = x.flat[r*512+j],
    // 81<=r<162 = K1.flat[(r-81)*512+j], r>=162 = 0. 6 K-passes of 32.
    {
        const int wv = t >> 6;          // wave 0..15, owns cols [wv*32, wv*32+32)
        const int lane = t & 63;
        const int quad = lane >> 4;
        const int l15 = lane & 15;
        const int nbase = wv * 32;
        const unsigned short* w1f = (const unsigned short*)(ws + WS_W1F);

        f32x4 acc[6][2];
        #pragma unroll
        for (int m = 0; m < 6; ++m)
            #pragma unroll
            for (int n = 0; n < 2; ++n)
                acc[m][n] = (f32x4){0.f, 0.f, 0.f, 0.f};

        #pragma unroll 1
        for (int pass = 0; pass < 6; ++pass) {
            // build kqT[col][rl] for rg = pass*32 + rl
            #pragma unroll 1
            for (int ii = 0; ii < 16; ++ii) {
                int idx = ii * 1024 + t;
                int j = idx & 511;
                int rl = idx >> 9;
                int rg = pass * 32 + rl;
                unsigned short val;
                if (rg < 81) {
                    val = xb[rg * 512 + j];
                } else if (rg < 162) {
                    int e = (rg - 81) * 512 + j;
                    int p = e % 81;
                    float s = bseb[p];
                    #pragma unroll
                    for (int tau = 0; tau < 9; ++tau) {
                        int flat = e + (tau - 4) * 81;
                        if (flat >= 0 && flat < CH)
                            s = fmaf(h2f(xb[flat]), wseT[tau * 81 + p], s);
                    }
                    val = f2h(s);
                } else {
                    val = 0;
                }
                kqT[j * KST + rl] = val;
            }
            __syncthreads();
            half8 bfr[2];
            #pragma unroll
            for (int n = 0; n < 2; ++n)
                bfr[n] = *(const half8*)&kqT[(nbase + n * 16 + l15) * KST + quad * 8];
            #pragma unroll
            for (int m = 0; m < 6; ++m) {
                half8 afr = *(const half8*)&w1f[(m * 16 + l15) * 192 + pass * 32 + quad * 8];
                acc[m][0] = __builtin_amdgcn_mfma_f32_16x16x32_f16(afr, bfr[0], acc[m][0], 0, 0, 0);
                acc[m][1] = __builtin_amdgcn_mfma_f32_16x16x32_f16(afr, bfr[1], acc[m][1], 0, 0, 0);
            }
            __syncthreads();
        }

        // epilogue: relu(C + tse) -> fold 9x81 -> softmax -> ws ATT
        float* attout = ws + WS_ATT + (size_t)b * 4608;
        #pragma unroll
        for (int n = 0; n < 2; ++n) {
            float pd[9];
            #pragma unroll
            for (int d = 0; d < 9; ++d) pd[d] = 0.f;
            #pragma unroll
            for (int m = 0; m < 6; ++m) {
                #pragma unroll
                for (int reg = 0; reg < 4; ++reg) {
                    int row = m * 16 + quad * 4 + reg;
                    float z = fmaxf(acc[m][n][reg] + tseL[row], 0.f);
                    #pragma unroll
                    for (int d = 0; d < 9; ++d)
                        pd[d] = fmaf(w2L[d * 96 + row], z, pd[d]);
                }
            }
            #pragma unroll
            for (int d = 0; d < 9; ++d) {
                pd[d] += __shfl_xor(pd[d], 16, 64);
                pd[d] += __shfl_xor(pd[d], 32, 64);
            }
            if (quad == 0) {
                int j = nbase + n * 16 + l15;
                float ad[9];
                #pragma unroll
                for (int d = 0; d < 9; ++d) ad[d] = pd[d] + se_att_b2[d];
                float mm = ad[0];
                #pragma unroll
                for (int d = 1; d < 9; ++d) mm = fmaxf(mm, ad[d]);
                float ls = 0.f;
                #pragma unroll
                for (int d = 0; d < 9; ++d) { ad[d] = __expf(ad[d] - mm); ls += ad[d]; }
                float inv = 1.f / ls;
                #pragma unroll
                for (int d = 0; d < 9; ++d) attout[d * 512 + j] = ad[d] * inv;
            }
        }
    }
}

// ============== Kernel B: combine, block = (batch, 64-channel tile) =========
__global__ __launch_bounds__(256) void combine_kernel(
    const float* __restrict__ x,
    const float* __restrict__ alpha,
    const float* __restrict__ sa_key_w,   // 512*9
    const float* __restrict__ se_key_w,   // 81*9
    const float* __restrict__ se_key_b,   // 81
    const float* __restrict__ se_val_w,   // 512*9
    const float* __restrict__ se_val_b,   // 512
    const float* __restrict__ ws,
    float* __restrict__ out)
{
    __shared__ float xs[72 * 81];   // channels c0-4 .. c0+67 (zero-pad OOB)
    __shared__ float vs[72 * 81];   // depthwise-v plane (zero OOB, matches pad_v)
    __shared__ float wvL[72 * 9];
    __shared__ float bvL[72];
    __shared__ float wkL[64 * 9];
    __shared__ float s2L[64];
    __shared__ float t2L[64];
    __shared__ float wseL[81 * 9];
    __shared__ float bseL[81];
    __shared__ float attL[9 * 64];
    __shared__ float a2L[8 * 81];
    /* ~60.5 KB */

    const int bid = blockIdx.x;
    const int b = bid >> 3;
    const int tile = bid & 7;
    const int c0 = tile * 64;
    const int t = threadIdx.x;
    const int f0 = (c0 - 4) * 81;

    for (int idx = t; idx < 5832; idx += 256) {
        int g = f0 + idx;
        xs[idx] = (g >= 0 && g < CH) ? x[(size_t)b * CH + g] : 0.f;
    }
    for (int idx = t; idx < 648; idx += 256) {
        int cc = c0 - 4 + idx / 9;
        wvL[idx] = (cc >= 0 && cc < 512) ? se_val_w[cc * 9 + idx % 9] : 0.f;
    }
    if (t < 72) {
        int cc = c0 - 4 + t;
        bvL[t] = (cc >= 0 && cc < 512) ? se_val_b[cc] : 0.f;
    }
    for (int idx = t; idx < 576; idx += 256) wkL[idx] = sa_key_w[c0 * 9 + idx];
    if (t < 64) { s2L[t] = ws[WS_S2 + c0 + t]; t2L[t] = ws[WS_T2 + c0 + t]; }
    for (int idx = t; idx < 729; idx += 256) wseL[idx] = se_key_w[idx];
    if (t < 81) bseL[t] = se_key_b[t];
    for (int idx = t; idx < 576; idx += 256)
        attL[idx] = ws[WS_ATT + (size_t)b * 4608 + (idx >> 6) * 512 + c0 + (idx & 63)];
    for (int idx = t; idx < 648; idx += 256)
        a2L[idx] = ws[WS_A2 + (size_t)b * 5184 + tile * 648 + idx];
    __syncthreads();

    // depthwise-v plane (3x3 conv + bias), zero for OOB channels (= pad_v)
    for (int idx = t; idx < 5832; idx += 256) {
        int i = idx / 81, p = idx - 81 * i;
        int cc = c0 - 4 + i;
        float r = 0.f;
        if (cc >= 0 && cc < 512) {
            int y = p / 9, xx = p - 9 * (p / 9);
            float s = 0.f;
            #pragma unroll
            for (int ky = 0; ky < 3; ++ky) {
                int yy = y + ky - 1;
                if (yy < 0 || yy > 8) continue;
                #pragma unroll
                for (int kx = 0; kx < 3; ++kx) {
                    int xc = xx + kx - 1;
                    if (xc < 0 || xc > 8) continue;
                    s = fmaf(xs[i * 81 + yy * 9 + xc], wvL[i * 9 + ky * 3 + kx], s);
                }
            }
            r = s + bvL[i];
        }
        vs[idx] = r;
    }
    __syncthreads();

    const float av = alpha[0];
    float* outb = out + (size_t)b * CH + (size_t)c0 * 81;
    #pragma unroll 1
    for (int e = t; e < 5184; e += 256) {
        int cl = e / 81, p = e - 81 * cl;
        int y = p / 9, xx = p - 9 * y;
        // spatial key (3x3 dw conv -> bn -> relu)
        float sk = 0.f;
        #pragma unroll
        for (int ky = 0; ky < 3; ++ky) {
            int yy = y + ky - 1;
            if (yy < 0 || yy > 8) continue;
            #pragma unroll
            for (int kx = 0; kx < 3; ++kx) {
                int xc = xx + kx - 1;
                if (xc < 0 || xc > 8) continue;
                sk = fmaf(xs[(cl + 4) * 81 + yy * 9 + xc], wkL[cl * 9 + ky * 3 + kx], sk);
            }
        }
        float k1s = fmaxf(sk * s2L[cl] + t2L[cl], 0.f);
        // spectral attention combine
        float o1 = 0.f;
        #pragma unroll
        for (int d = 0; d < 9; ++d)
            o1 = fmaf(vs[(cl + d) * 81 + p], attL[d * 64 + cl], o1);
        // spectral key value (k1) added to out1
        float k1se = bseL[p];
        #pragma unroll
        for (int tau = 0; tau < 9; ++tau)
            k1se = fmaf(xs[(cl + tau) * 81 + p], wseL[p * 9 + tau], k1se);
        float out2 = k1s + a2L[(cl >> 3) * 81 + p] * xs[(cl + 4) * 81 + p];
        outb[cl * 81 + p] = av * (o1 + k1se) + (1.f - av) * out2;
    }
}

extern "C" void kernel_launch(void* const* d_in, const int* in_sizes, int n_in,
                              void* d_out, int out_size, void* d_ws, size_t ws_size,
                              hipStream_t stream) {
    const float* x          = (const float*)d_in[0];
    const float* alpha      = (const float*)d_in[1];
    const float* sa_key_w   = (const float*)d_in[2];
    const float* sa_key_bn  = (const float*)d_in[3];
    const float* sa_att_w1  = (const float*)d_in[4];
    const float* sa_att_bn  = (const float*)d_in[5];
    const float* sa_att_w2  = (const float*)d_in[6];
    const float* sa_att_b2  = (const float*)d_in[7];
    const float* se_key_w   = (const float*)d_in[8];
    const float* se_key_b   = (const float*)d_in[9];
    const float* se_att_w1  = (const float*)d_in[10];
    const float* se_att_bn  = (const float*)d_in[11];
    const float* se_att_w2  = (const float*)d_in[12];
    const float* se_att_b2  = (const float*)d_in[13];
    const float* se_val_w   = (const float*)d_in[14];
    const float* se_val_b   = (const float*)d_in[15];
    float* ws = (float*)d_ws;
    float* outp = (float*)d_out;

    prep_kernel<<<(PREP_N + 255) / 256, 256, 0, stream>>>(
        se_att_w1, se_att_bn, sa_key_bn, sa_att_w1, sa_att_bn, ws);
    attn_kernel<<<BSZ, 1024, 0, stream>>>(
        x, sa_key_w, sa_att_w2, sa_att_b2,
        se_key_w, se_key_b, se_att_w2, se_att_b2, ws);
    combine_kernel<<<BSZ * 8, 256, 0, stream>>>(
        x, alpha, sa_key_w, se_key_w, se_key_b, se_val_w, se_val_b, ws, outp);
}

// Round 6
// 685.307 us; speedup vs baseline: 1.2140x; 1.2140x over previous
//
#include <hip/hip_runtime.h>
#include <hip/hip_fp16.h>

#define BSZ 256
#define CCH 512
#define HW_ 81
#define DD 9
#define CH 41472   /* CCH*HW_ */

/* ws layout (floats) */
#define WS_W1T   0        /* [162][81] folded+transposed se_att_w1 (legacy, unused) */
#define WS_TSE   13122    /* [81]  folded se_att bias */
#define WS_S2    13203    /* [512] sa_key bn scale */
#define WS_T2    13715    /* [512] sa_key bn bias */
#define WS_W1S   14227    /* [512][16] folded sa_att_w1 */
#define WS_T1    22419    /* [512] folded sa_att bias */
#define WS_A2    22932    /* [256][64][81] SaMCA attention */
#define WS_ATT   1350036  /* [256][9][512] SeMCA attention */
#define WS_W1F   2529684  /* [96][192] fp16 folded se_att_w1, zero-padded (ushorts) */
#define WS_TOTALP 22931   /* params region end */
#define PREP_N   41363    /* 22931 + 96*192/2 */

#define KST 40            /* kqT row stride in elements (80 B, 16B-aligned) */

typedef _Float16 half8 __attribute__((ext_vector_type(8)));
typedef float f32x4 __attribute__((ext_vector_type(4)));

__device__ __forceinline__ float h2f(unsigned short u) {
    return __half2float(__ushort_as_half(u));
}
__device__ __forceinline__ unsigned short f2h(float f) {
    return __half_as_ushort(__float2half(f));
}

__global__ void prep_kernel(const float* __restrict__ se_att_w1,  // 81*162
                            const float* __restrict__ se_att_bn,  // 4*81
                            const float* __restrict__ sa_key_bn,  // 4*512
                            const float* __restrict__ sa_att_w1,  // 512*16
                            const float* __restrict__ sa_att_bn,  // 4*512
                            float* __restrict__ ws) {
    int idx = blockIdx.x * blockDim.x + threadIdx.x;
    if (idx < 13122) {
        int r = idx / 81, o = idx % 81;
        float g = se_att_bn[o], v = se_att_bn[243 + o];
        float s = g * rsqrtf(v + 1e-5f);
        ws[WS_W1T + idx] = se_att_w1[o * 162 + r] * s;
    } else if (idx < 13203) {
        int o = idx - 13122;
        float g = se_att_bn[o], b = se_att_bn[81 + o], m = se_att_bn[162 + o], v = se_att_bn[243 + o];
        float s = g * rsqrtf(v + 1e-5f);
        ws[WS_TSE + o] = b - m * s;
    } else if (idx < 13715) {
        int c = idx - 13203;
        float g = sa_key_bn[c], v = sa_key_bn[1536 + c];
        ws[WS_S2 + c] = g * rsqrtf(v + 1e-5f);
    } else if (idx < 14227) {
        int c = idx - 13715;
        float g = sa_key_bn[c], b = sa_key_bn[512 + c], m = sa_key_bn[1024 + c], v = sa_key_bn[1536 + c];
        float s = g * rsqrtf(v + 1e-5f);
        ws[WS_T2 + c] = b - m * s;
    } else if (idx < 22419) {
        int e = idx - 14227;
        int o = e >> 4;
        float g = sa_att_bn[o], v = sa_att_bn[1536 + o];
        float s = g * rsqrtf(v + 1e-5f);
        ws[WS_W1S + e] = sa_att_w1[e] * s;
    } else if (idx < WS_TOTALP) {
        int o = idx - 22419;
        float g = sa_att_bn[o], b = sa_att_bn[512 + o], m = sa_att_bn[1024 + o], v = sa_att_bn[1536 + o];
        float s = g * rsqrtf(v + 1e-5f);
        ws[WS_T1 + o] = b - m * s;
    } else if (idx < PREP_N) {
        // fp16 folded W1, padded [96][192] (two ushorts per float slot)
        int e2 = (idx - WS_TOTALP) * 2;
        unsigned int packed = 0;
        #pragma unroll
        for (int q = 0; q < 2; ++q) {
            int e = e2 + q;
            int row = e / 192, k = e - row * 192;
            unsigned short val = 0;
            if (row < 81 && k < 162) {
                float g = se_att_bn[row], v = se_att_bn[243 + row];
                float s = g * rsqrtf(v + 1e-5f);
                val = f2h(se_att_w1[row * 162 + k] * s);
            }
            packed |= ((unsigned int)val) << (16 * q);
        }
        ((unsigned int*)(ws + WS_W1F))[idx - WS_TOTALP] = packed;
    }
}

// ======== Kernel A: attention, grid = (batch, col-half), 256 threads ========
// 256-thr blocks => compiler VGPR cap 256 (observed cap = 65536/blockDim):
// 512-thr gave 128, 1024-thr gave 64 -> P2 accumulators spilled (654 MB HBM).
__global__ __launch_bounds__(256) void attn_kernel(
    const float* __restrict__ x,
    const float* __restrict__ sa_key_w,   // 512*9
    const float* __restrict__ sa_att_w2,  // 64*8
    const float* __restrict__ sa_att_b2,  // 64
    const float* __restrict__ se_key_w,   // 81*9
    const float* __restrict__ se_key_b,   // 81
    const float* __restrict__ se_att_w2,  // 9*81
    const float* __restrict__ se_att_b2,  // 9
    float* __restrict__ ws)
{
    __shared__ __align__(16) unsigned short xb[CH];        // 82944 B, x[b] fp16
    __shared__ __align__(16) unsigned short kqT[256 * KST];// 20480 B
    __shared__ unsigned short wkbL[256 * DD];              //  4608 B (this half's ch)
    __shared__ float s2L[256];                             //  1024 B
    __shared__ float t2L[256];                             //  1024 B
    __shared__ float wseT[DD * HW_];                       //  2916 B (wseT[tau][p])
    __shared__ float bseb[HW_];                            //   324 B
    __shared__ float w2L[DD * 96];                         //  3456 B
    __shared__ float tseL[96];                             //   384 B
    __shared__ float w1sL[256 * 16];                       // 16384 B (this half's rows)
    __shared__ float saw2L[256];                           //  1024 B
    __shared__ float b2L[32];                              //   128 B
    __shared__ float t1L[256];                             //  1024 B
    /* total ~135.7 KB */

    const int bid = blockIdx.x;
    const int b = bid >> 1;
    const int h = bid & 1;
    const int c0 = h * 256;        // this block's column/channel range start
    const int t = threadIdx.x;

    // ---- P0: stage ----
    {
        const float4* x4 = (const float4*)(x + (size_t)b * CH);
        for (int v = t; v < CH / 4; v += 256) {
            float4 q = x4[v];
            ushort4 s4;
            s4.x = f2h(q.x); s4.y = f2h(q.y); s4.z = f2h(q.z); s4.w = f2h(q.w);
            *(ushort4*)(&xb[4 * v]) = s4;
        }
        for (int v = t; v < 256 * DD; v += 256) wkbL[v] = f2h(sa_key_w[c0 * 9 + v]);
        if (t < 256) { s2L[t] = ws[WS_S2 + c0 + t]; t2L[t] = ws[WS_T2 + c0 + t]; }
        for (int v = t; v < DD * HW_; v += 256) {
            int tau = v / 81, p = v - 81 * tau;
            wseT[tau * 81 + p] = se_key_w[p * 9 + tau];
        }
        if (t < HW_) bseb[t] = se_key_b[t];
        for (int v = t; v < DD * 96; v += 256) {
            int d = v / 96, row = v - 96 * d;
            w2L[v] = (row < 81) ? se_att_w2[d * 81 + row] : 0.f;
        }
        if (t < 96) tseL[t] = (t < 81) ? ws[WS_TSE + t] : 0.f;
        for (int v = t; v < 256 * 16; v += 256) w1sL[v] = ws[WS_W1S + c0 * 16 + v];
        saw2L[t] = sa_att_w2[c0 + t];          // groups h*32.. : 32*8 = 256 floats
        if (t < 32) b2L[t] = sa_att_b2[h * 32 + t];
        t1L[t] = ws[WS_T1 + c0 + t];
    }
    __syncthreads();

    // ---- P1: SaMCA attention for groups [h*32, h*32+32) -> ws A2 ----
    {
        const int gl = t >> 3, sub = t & 7;     // local group 0..31, 8 lanes each
        const int g = h * 32 + gl;
        const float b2g = b2L[gl];
        float a2v[11];
        #pragma unroll
        for (int k = 0; k < 11; ++k) {
            int p = sub + 8 * k;
            float res = -1e30f;
            if (p < 81) {
                int y = p / 9, xx = p - (p / 9) * 9;
                float z[8];
                #pragma unroll
                for (int o = 0; o < 8; ++o) z[o] = t1L[8 * gl + o];
                #pragma unroll
                for (int j = 0; j < 8; ++j) {
                    int cl = 8 * gl + j;        // local channel
                    int c = c0 + cl;            // global channel
                    float conv = 0.f;
                    #pragma unroll
                    for (int ky = 0; ky < 3; ++ky) {
                        int yy = y + ky - 1;
                        if (yy < 0 || yy > 8) continue;
                        #pragma unroll
                        for (int kx = 0; kx < 3; ++kx) {
                            int xc = xx + kx - 1;
                            if (xc < 0 || xc > 8) continue;
                            conv = fmaf(h2f(xb[c * 81 + yy * 9 + xc]),
                                        h2f(wkbL[cl * 9 + ky * 3 + kx]), conv);
                        }
                    }
                    float kv = fmaxf(conv * s2L[cl] + t2L[cl], 0.f);
                    float xv = h2f(xb[c * 81 + p]);
                    #pragma unroll
                    for (int o = 0; o < 8; ++o) {
                        const float* w1o = &w1sL[(8 * gl + o) * 16];
                        z[o] = fmaf(w1o[2 * j], kv, z[o]);
                        z[o] = fmaf(w1o[2 * j + 1], xv, z[o]);
                    }
                }
                float s = b2g;
                #pragma unroll
                for (int o = 0; o < 8; ++o)
                    s = fmaf(saw2L[gl * 8 + o], fmaxf(z[o], 0.f), s);
                res = s;
            }
            a2v[k] = res;
        }
        float m = a2v[0];
        #pragma unroll
        for (int k = 1; k < 11; ++k) m = fmaxf(m, a2v[k]);
        #pragma unroll
        for (int off = 1; off < 8; off <<= 1) m = fmaxf(m, __shfl_xor(m, off, 64));
        float ls = 0.f;
        float ev[11];
        #pragma unroll
        for (int k = 0; k < 11; ++k) { ev[k] = __expf(a2v[k] - m); ls += ev[k]; }
        #pragma unroll
        for (int off = 1; off < 8; off <<= 1) ls += __shfl_xor(ls, off, 64);
        float inv = 1.f / ls;
        float* a2out = ws + WS_A2 + (size_t)b * 5184;
        #pragma unroll
        for (int k = 0; k < 11; ++k) {
            int p = sub + 8 * k;
            if (p < 81) a2out[g * 81 + p] = ev[k] * inv;
        }
    }

    // ---- P2: SeMCA attention via MFMA, columns [c0, c0+256) ----
    // C[96 x 256] = W1f[96 x 192] * KQ[192 x 256-slice]; 6 K-passes of 32.
    {
        const int wv = t >> 6;          // wave 0..3, owns cols [c0+wv*64, +64)
        const int lane = t & 63;
        const int quad = lane >> 4;
        const int l15 = lane & 15;
        const unsigned short* w1f = (const unsigned short*)(ws + WS_W1F);

        f32x4 acc[6][4];
        #pragma unroll
        for (int m = 0; m < 6; ++m)
            #pragma unroll
            for (int n = 0; n < 4; ++n)
                acc[m][n] = (f32x4){0.f, 0.f, 0.f, 0.f};

        #pragma unroll 1
        for (int pass = 0; pass < 6; ++pass) {
            // build kqT[jl][rl]; idx = rl*256 + jl, per ii: rl = ii, jl = t
            #pragma unroll 1
            for (int ii = 0; ii < 32; ++ii) {
                int jl = t;
                int rg = pass * 32 + ii;
                int j = c0 + jl;
                unsigned short val;
                if (rg < 81) {
                    val = xb[rg * 512 + j];
                } else if (rg < 162) {
                    int e = (rg - 81) * 512 + j;
                    int p = e % 81;
                    float s = bseb[p];
                    #pragma unroll
                    for (int tau = 0; tau < 9; ++tau) {
                        int flat = e + (tau - 4) * 81;
                        if (flat >= 0 && flat < CH)
                            s = fmaf(h2f(xb[flat]), wseT[tau * 81 + p], s);
                    }
                    val = f2h(s);
                } else {
                    val = 0;
                }
                kqT[jl * KST + ii] = val;
            }
            __syncthreads();
            half8 bfr[4];
            #pragma unroll
            for (int n = 0; n < 4; ++n)
                bfr[n] = *(const half8*)&kqT[(wv * 64 + n * 16 + l15) * KST + quad * 8];
            #pragma unroll
            for (int m = 0; m < 6; ++m) {
                half8 afr = *(const half8*)&w1f[(m * 16 + l15) * 192 + pass * 32 + quad * 8];
                #pragma unroll
                for (int n = 0; n < 4; ++n)
                    acc[m][n] = __builtin_amdgcn_mfma_f32_16x16x32_f16(afr, bfr[n], acc[m][n], 0, 0, 0);
            }
            __syncthreads();
        }

        // epilogue: relu(C + tse) -> fold 9x81 -> softmax -> ws ATT
        float* attout = ws + WS_ATT + (size_t)b * 4608;
        #pragma unroll 1
        for (int n = 0; n < 4; ++n) {
            float pd[9];
            #pragma unroll
            for (int d = 0; d < 9; ++d) pd[d] = 0.f;
            #pragma unroll
            for (int m = 0; m < 6; ++m) {
                #pragma unroll
                for (int reg = 0; reg < 4; ++reg) {
                    int row = m * 16 + quad * 4 + reg;
                    float z = fmaxf(acc[m][n][reg] + tseL[row], 0.f);
                    #pragma unroll
                    for (int d = 0; d < 9; ++d)
                        pd[d] = fmaf(w2L[d * 96 + row], z, pd[d]);
                }
            }
            #pragma unroll
            for (int d = 0; d < 9; ++d) {
                pd[d] += __shfl_xor(pd[d], 16, 64);
                pd[d] += __shfl_xor(pd[d], 32, 64);
            }
            if (quad == 0) {
                int j = c0 + wv * 64 + n * 16 + l15;
                float ad[9];
                #pragma unroll
                for (int d = 0; d < 9; ++d) ad[d] = pd[d] + se_att_b2[d];
                float mm = ad[0];
                #pragma unroll
                for (int d = 1; d < 9; ++d) mm = fmaxf(mm, ad[d]);
                float ls = 0.f;
                #pragma unroll
                for (int d = 0; d < 9; ++d) { ad[d] = __expf(ad[d] - mm); ls += ad[d]; }
                float inv = 1.f / ls;
                #pragma unroll
                for (int d = 0; d < 9; ++d) attout[d * 512 + j] = ad[d] * inv;
            }
        }
    }
}

// ============== Kernel B: combine, block = (batch, 64-channel tile) =========
__global__ __launch_bounds__(256) void combine_kernel(
    const float* __restrict__ x,
    const float* __restrict__ alpha,
    const float* __restrict__ sa_key_w,   // 512*9
    const float* __restrict__ se_key_w,   // 81*9
    const float* __restrict__ se_key_b,   // 81
    const float* __restrict__ se_val_w,   // 512*9
    const float* __restrict__ se_val_b,   // 512
    const float* __restrict__ ws,
    float* __restrict__ out)
{
    __shared__ float xs[72 * 81];   // channels c0-4 .. c0+67 (zero-pad OOB)
    __shared__ float vs[72 * 81];   // depthwise-v plane (zero OOB, matches pad_v)
    __shared__ float wvL[72 * 9];
    __shared__ float bvL[72];
    __shared__ float wkL[64 * 9];
    __shared__ float s2L[64];
    __shared__ float t2L[64];
    __shared__ float wseL[81 * 9];
    __shared__ float bseL[81];
    __shared__ float attL[9 * 64];
    __shared__ float a2L[8 * 81];
    /* ~60.5 KB */

    const int bid = blockIdx.x;
    const int b = bid >> 3;
    const int tile = bid & 7;
    const int c0 = tile * 64;
    const int t = threadIdx.x;
    const int f0 = (c0 - 4) * 81;

    for (int idx = t; idx < 5832; idx += 256) {
        int g = f0 + idx;
        xs[idx] = (g >= 0 && g < CH) ? x[(size_t)b * CH + g] : 0.f;
    }
    for (int idx = t; idx < 648; idx += 256) {
        int cc = c0 - 4 + idx / 9;
        wvL[idx] = (cc >= 0 && cc < 512) ? se_val_w[cc * 9 + idx % 9] : 0.f;
    }
    if (t < 72) {
        int cc = c0 - 4 + t;
        bvL[t] = (cc >= 0 && cc < 512) ? se_val_b[cc] : 0.f;
    }
    for (int idx = t; idx < 576; idx += 256) wkL[idx] = sa_key_w[c0 * 9 + idx];
    if (t < 64) { s2L[t] = ws[WS_S2 + c0 + t]; t2L[t] = ws[WS_T2 + c0 + t]; }
    for (int idx = t; idx < 729; idx += 256) wseL[idx] = se_key_w[idx];
    if (t < 81) bseL[t] = se_key_b[t];
    for (int idx = t; idx < 576; idx += 256)
        attL[idx] = ws[WS_ATT + (size_t)b * 4608 + (idx >> 6) * 512 + c0 + (idx & 63)];
    for (int idx = t; idx < 648; idx += 256)
        a2L[idx] = ws[WS_A2 + (size_t)b * 5184 + tile * 648 + idx];
    __syncthreads();

    // depthwise-v plane (3x3 conv + bias), zero for OOB channels (= pad_v)
    for (int idx = t; idx < 5832; idx += 256) {
        int i = idx / 81, p = idx - 81 * i;
        int cc = c0 - 4 + i;
        float r = 0.f;
        if (cc >= 0 && cc < 512) {
            int y = p / 9, xx = p - 9 * (p / 9);
            float s = 0.f;
            #pragma unroll
            for (int ky = 0; ky < 3; ++ky) {
                int yy = y + ky - 1;
                if (yy < 0 || yy > 8) continue;
                #pragma unroll
                for (int kx = 0; kx < 3; ++kx) {
                    int xc = xx + kx - 1;
                    if (xc < 0 || xc > 8) continue;
                    s = fmaf(xs[i * 81 + yy * 9 + xc], wvL[i * 9 + ky * 3 + kx], s);
                }
            }
            r = s + bvL[i];
        }
        vs[idx] = r;
    }
    __syncthreads();

    const float av = alpha[0];
    float* outb = out + (size_t)b * CH + (size_t)c0 * 81;
    #pragma unroll 1
    for (int e = t; e < 5184; e += 256) {
        int cl = e / 81, p = e - 81 * cl;
        int y = p / 9, xx = p - 9 * y;
        // spatial key (3x3 dw conv -> bn -> relu)
        float sk = 0.f;
        #pragma unroll
        for (int ky = 0; ky < 3; ++ky) {
            int yy = y + ky - 1;
            if (yy < 0 || yy > 8) continue;
            #pragma unroll
            for (int kx = 0; kx < 3; ++kx) {
                int xc = xx + kx - 1;
                if (xc < 0 || xc > 8) continue;
                sk = fmaf(xs[(cl + 4) * 81 + yy * 9 + xc], wkL[cl * 9 + ky * 3 + kx], sk);
            }
        }
        float k1s = fmaxf(sk * s2L[cl] + t2L[cl], 0.f);
        // spectral attention combine
        float o1 = 0.f;
        #pragma unroll
        for (int d = 0; d < 9; ++d)
            o1 = fmaf(vs[(cl + d) * 81 + p], attL[d * 64 + cl], o1);
        // spectral key value (k1) added to out1
        float k1se = bseL[p];
        #pragma unroll
        for (int tau = 0; tau < 9; ++tau)
            k1se = fmaf(xs[(cl + tau) * 81 + p], wseL[p * 9 + tau], k1se);
        float out2 = k1s + a2L[(cl >> 3) * 81 + p] * xs[(cl + 4) * 81 + p];
        outb[cl * 81 + p] = av * (o1 + k1se) + (1.f - av) * out2;
    }
}

extern "C" void kernel_launch(void* const* d_in, const int* in_sizes, int n_in,
                              void* d_out, int out_size, void* d_ws, size_t ws_size,
                              hipStream_t stream) {
    const float* x          = (const float*)d_in[0];
    const float* alpha      = (const float*)d_in[1];
    const float* sa_key_w   = (const float*)d_in[2];
    const float* sa_key_bn  = (const float*)d_in[3];
    const float* sa_att_w1  = (const float*)d_in[4];
    const float* sa_att_bn  = (const float*)d_in[5];
    const float* sa_att_w2  = (const float*)d_in[6];
    const float* sa_att_b2  = (const float*)d_in[7];
    const float* se_key_w   = (const float*)d_in[8];
    const float* se_key_b   = (const float*)d_in[9];
    const float* se_att_w1  = (const float*)d_in[10];
    const float* se_att_bn  = (const float*)d_in[11];
    const float* se_att_w2  = (const float*)d_in[12];
    const float* se_att_b2  = (const float*)d_in[13];
    const float* se_val_w   = (const float*)d_in[14];
    const float* se_val_b   = (const float*)d_in[15];
    float* ws = (float*)d_ws;
    float* outp = (float*)d_out;

    prep_kernel<<<(PREP_N + 255) / 256, 256, 0, stream>>>(
        se_att_w1, se_att_bn, sa_key_bn, sa_att_w1, sa_att_bn, ws);
    attn_kernel<<<BSZ * 2, 256, 0, stream>>>(
        x, sa_key_w, sa_att_w2, sa_att_b2,
        se_key_w, se_key_b, se_att_w2, se_att_b2, ws);
    combine_kernel<<<BSZ * 8, 256, 0, stream>>>(
        x, alpha, sa_key_w, se_key_w, se_key_b, se_val_w, se_val_b, ws, outp);
}